// Round 14
// baseline (503.211 us; speedup 1.0000x reference)
//
#include <hip/hip_runtime.h>
#include <hip/hip_bf16.h>
#include <math.h>

// Problem constants
constexpr int cB = 4, cT = 256, cS = 400, cD = 512, cV = 50000, cNX = 50;
constexpr int cVEXT = cV + cNX;           // 50050
constexpr int cPAN  = (cV + 127) / 128;   // 391 col panels (128-wide)
constexpr int cCBLD = cVEXT * 2;          // ushort stride of one fp32 out row
constexpr int cTOP  = 50100;              // ushort offset of bf16 logits in-slot
constexpr int cMQ   = cB * cT;            // 1024

typedef __attribute__((ext_vector_type(8))) short short8v;   // 8 bf16
typedef __attribute__((ext_vector_type(4))) float floatx4;

__device__ inline ushort f2bf(float f) {
    union { float f; unsigned u; } v; v.f = f;
    unsigned r = (v.u + 0x7FFFu + ((v.u >> 16) & 1u)) >> 16;
    return (ushort)r;
}
__device__ inline float bf2f(ushort u) {
    union { unsigned u; float f; } v; v.u = ((unsigned)u) << 16;
    return v.f;
}

// ---------------------------------------------------------------------------
// fp32 -> bf16 cast (large buffers)
// ---------------------------------------------------------------------------
__global__ __launch_bounds__(256) void cast_kernel(
    const float* __restrict__ src, ushort* __restrict__ dst, int n4)
{
    const int stride = gridDim.x * 256;
    for (int i = blockIdx.x * 256 + threadIdx.x; i < n4; i += stride) {
        float4 v = *(const float4*)(src + (size_t)i * 4);
        ushort4 o;
        o.x = f2bf(v.x); o.y = f2bf(v.y); o.z = f2bf(v.z); o.w = f2bf(v.w);
        *(ushort4*)(dst + (size_t)i * 4) = o;
    }
}

// ---------------------------------------------------------------------------
// Fused 4-segment cast (x, enc, wq, wk) -- one launch instead of four.
// ---------------------------------------------------------------------------
__global__ __launch_bounds__(256) void cast4_kernel(
    const float* __restrict__ s0, ushort* __restrict__ d0, int n0,
    const float* __restrict__ s1, ushort* __restrict__ d1, int n1,
    const float* __restrict__ s2, ushort* __restrict__ d2, int n2,
    const float* __restrict__ s3, ushort* __restrict__ d3, int n3)
{
    const int stride = gridDim.x * 256;
    const int base = blockIdx.x * 256 + threadIdx.x;
    const float* ss[4] = {s0, s1, s2, s3};
    ushort*      dd[4] = {d0, d1, d2, d3};
    const int    nn[4] = {n0, n1, n2, n3};
    #pragma unroll
    for (int seg = 0; seg < 4; ++seg) {
        const float* s = ss[seg]; ushort* d = dd[seg]; const int n = nn[seg];
        for (int i = base; i < n; i += stride) {
            float4 v = *(const float4*)(s + (size_t)i * 4);
            ushort4 o;
            o.x = f2bf(v.x); o.y = f2bf(v.y); o.z = f2bf(v.z); o.w = f2bf(v.w);
            *(ushort4*)(d + (size_t)i * 4) = o;
        }
    }
}

// ---------------------------------------------------------------------------
// Small bf16 MFMA GEMM (projections): 128x128 tile, BK=32, 4 waves, frag-order
// LDS, fp32 C + bias. Plain block mapping. (r11-proven.)
// ---------------------------------------------------------------------------
__global__ __launch_bounds__(256) void gemm_proj(
    const ushort* __restrict__ A, const ushort* __restrict__ Wb,
    const float* __restrict__ bias, float* __restrict__ Cf,
    int M, int N, int K, int ldc)
{
    __shared__ ushort As[2][128 * 32];
    __shared__ ushort Bs[2][128 * 32];

    const int tid  = threadIdx.x;
    const int lane = tid & 63;
    const int wv   = tid >> 6;
    const int wm   = wv >> 1;
    const int wn   = wv & 1;
    const int bm   = blockIdx.x * 128;
    const int bn   = blockIdx.y * 128;

    const int rA = lane & 15;
    const int kA = (lane >> 4) * 8;
    const int nt = K >> 5;

    floatx4 acc[4][4] = {};

    auto stage = [&](int bidx, int t) {
        const int k0 = t * 32;
        #pragma unroll
        for (int c = 0; c < 2; ++c) {
            const int chunk = wv * 2 + c;
            int ga = bm + chunk * 16 + rA; if (ga >= M) ga = M - 1;
            __builtin_amdgcn_global_load_lds(
                (const __attribute__((address_space(1))) void*)(A + (size_t)ga * K + k0 + kA),
                (__attribute__((address_space(3))) void*)&As[bidx][chunk * 512], 16, 0, 0);
            int gb = bn + chunk * 16 + rA; if (gb >= N) gb = N - 1;
            __builtin_amdgcn_global_load_lds(
                (const __attribute__((address_space(1))) void*)(Wb + (size_t)gb * K + k0 + kA),
                (__attribute__((address_space(3))) void*)&Bs[bidx][chunk * 512], 16, 0, 0);
        }
    };

    stage(0, 0);
    __syncthreads();

    int buf = 0;
    for (int t = 0; t < nt; ++t) {
        if (t + 1 < nt) stage(buf ^ 1, t + 1);
        short8v a[4], b[4];
        #pragma unroll
        for (int mi = 0; mi < 4; ++mi)
            a[mi] = *(const short8v*)&As[buf][(wm * 4 + mi) * 512 + lane * 8];
        #pragma unroll
        for (int ni = 0; ni < 4; ++ni)
            b[ni] = *(const short8v*)&Bs[buf][(wn * 4 + ni) * 512 + lane * 8];
        #pragma unroll
        for (int mi = 0; mi < 4; ++mi)
            #pragma unroll
            for (int ni = 0; ni < 4; ++ni)
                acc[mi][ni] = __builtin_amdgcn_mfma_f32_16x16x32_bf16(
                    a[mi], b[ni], acc[mi][ni], 0, 0, 0);
        __syncthreads();
        buf ^= 1;
    }

    const int fr = lane & 15;
    const int g  = lane >> 4;
    #pragma unroll
    for (int mi = 0; mi < 4; ++mi) {
        #pragma unroll
        for (int ni = 0; ni < 4; ++ni) {
            const int colg = bn + wn * 64 + ni * 16 + fr;
            if (colg >= N) continue;
            const float bv = bias[colg];
            #pragma unroll
            for (int r = 0; r < 4; ++r) {
                const int row = bm + wm * 64 + mi * 16 + g * 4 + r;
                if (row < M) Cf[(size_t)row * ldc + colg] = acc[mi][ni][r] + bv;
            }
        }
    }
}

// ---------------------------------------------------------------------------
// Big logits GEMM: TALL tile 256x128 (two 128-row halves sharing the staged
// W tile), BK=32, 4 waves (2x2). Each wave: 32 MFMA / 12 ds_read per K-step
// (vs 16/8) -> halves barrier+staging cost per FLOP. [row][k] LDS (r7/r13
// proven layout). LDS 53KB -> 3 blocks/CU. Bijective XCD-chunked swizzle
// (nwg=1564, m204 general form). Writes bf16 logits into TOP half of each
// d_out row slot + transposed softmax partials pm[pan*cMQ + row].
// M=1024, K=512 (16 steps), N=cV.
// ---------------------------------------------------------------------------
__global__ __launch_bounds__(256) void gemm_big(
    const ushort* __restrict__ A, const ushort* __restrict__ Wb,
    const float* __restrict__ bias, ushort* __restrict__ Cb,
    float* __restrict__ pm, float* __restrict__ ps)
{
    __shared__ ushort As[2][2][128 * 32];   // [half][buf]
    __shared__ ushort Bs[2][128 * 32];
    __shared__ float sm_m[2][256];
    __shared__ float sm_s[2][256];

    const int tid  = threadIdx.x;
    const int lane = tid & 63;
    const int wv   = tid >> 6;
    const int wm   = wv >> 1;
    const int wn   = wv & 1;

    // bijective XCD-chunked swizzle: nwg = 4*391 = 1564, q=195, r=4
    const int wg  = blockIdx.y * gridDim.x + blockIdx.x;
    const int nwg = gridDim.x * gridDim.y;
    const int qq  = nwg >> 3, rr = nwg & 7;
    const int xcd = wg & 7;
    const int j   = (xcd < rr ? xcd * (qq + 1) : rr * (qq + 1) + (xcd - rr) * qq)
                  + (wg >> 3);
    const int pan = j >> 2;            // gridDim.x == 4 row-blocks
    const int bm  = (j & 3) * 256;
    const int bn  = pan * 128;

    const int srow = lane >> 2;        // 0..15
    const int sk   = (lane & 3) * 8;   // bf16 elems

    floatx4 acc[2][4][4] = {};

    auto stage = [&](int bidx, int t) {
        const int k0 = t * 32;
        #pragma unroll
        for (int h = 0; h < 2; ++h)
            #pragma unroll
            for (int c = 0; c < 2; ++c) {
                const int lr = wv * 32 + c * 16;
                const int ga = bm + h * 128 + lr + srow;   // M=1024, always valid
                __builtin_amdgcn_global_load_lds(
                    (const __attribute__((address_space(1))) void*)(A + (size_t)ga * cD + k0 + sk),
                    (__attribute__((address_space(3))) void*)&As[h][bidx][lr * 32], 16, 0, 0);
            }
        #pragma unroll
        for (int c = 0; c < 2; ++c) {
            const int lr = wv * 32 + c * 16;
            int gb = bn + lr + srow; if (gb >= cV) gb = cV - 1;
            __builtin_amdgcn_global_load_lds(
                (const __attribute__((address_space(1))) void*)(Wb + (size_t)gb * cD + k0 + sk),
                (__attribute__((address_space(3))) void*)&Bs[bidx][lr * 32], 16, 0, 0);
        }
    };

    stage(0, 0);
    __syncthreads();

    const int fr = lane & 15;
    const int g  = lane >> 4;
    int buf = 0;

    #pragma unroll 1
    for (int t = 0; t < 16; ++t) {
        if (t + 1 < 16) stage(buf ^ 1, t + 1);
        short8v a[2][4], b[4];
        #pragma unroll
        for (int h = 0; h < 2; ++h)
            #pragma unroll
            for (int mi = 0; mi < 4; ++mi)
                a[h][mi] = *(const short8v*)&As[h][buf][(wm * 64 + mi * 16 + fr) * 32 + g * 8];
        #pragma unroll
        for (int ni = 0; ni < 4; ++ni)
            b[ni] = *(const short8v*)&Bs[buf][(wn * 64 + ni * 16 + fr) * 32 + g * 8];
        #pragma unroll
        for (int h = 0; h < 2; ++h)
            #pragma unroll
            for (int mi = 0; mi < 4; ++mi)
                #pragma unroll
                for (int ni = 0; ni < 4; ++ni)
                    acc[h][mi][ni] = __builtin_amdgcn_mfma_f32_16x16x32_bf16(
                        a[h][mi], b[ni], acc[h][mi][ni], 0, 0, 0);
        __syncthreads();
        buf ^= 1;
    }

    // ---- epilogue: bias, per-row stats, bf16 top-half store ----
    float bv[4]; bool val[4];
    #pragma unroll
    for (int ni = 0; ni < 4; ++ni) {
        const int colg = bn + wn * 64 + ni * 16 + fr;
        val[ni] = (colg < cV);
        bv[ni] = val[ni] ? bias[colg] : 0.f;
    }
    #pragma unroll
    for (int h = 0; h < 2; ++h)
        #pragma unroll
        for (int mi = 0; mi < 4; ++mi)
            #pragma unroll
            for (int ni = 0; ni < 4; ++ni)
                #pragma unroll
                for (int r = 0; r < 4; ++r)
                    acc[h][mi][ni][r] += bv[ni];

    #pragma unroll
    for (int h = 0; h < 2; ++h) {
        #pragma unroll
        for (int mi = 0; mi < 4; ++mi) {
            #pragma unroll
            for (int r = 0; r < 4; ++r) {
                float mx = -1e30f;
                #pragma unroll
                for (int ni = 0; ni < 4; ++ni)
                    if (val[ni]) mx = fmaxf(mx, acc[h][mi][ni][r]);
                #pragma unroll
                for (int sw = 1; sw < 16; sw <<= 1)
                    mx = fmaxf(mx, __shfl_xor(mx, sw));
                float sm = 0.f;
                #pragma unroll
                for (int ni = 0; ni < 4; ++ni)
                    if (val[ni]) sm += __expf(acc[h][mi][ni][r] - mx);
                #pragma unroll
                for (int sw = 1; sw < 16; sw <<= 1)
                    sm += __shfl_xor(sm, sw);
                if (fr == 0) {
                    const int rl = h * 128 + wm * 64 + mi * 16 + g * 4 + r;
                    sm_m[wn][rl] = mx;
                    sm_s[wn][rl] = sm;
                }
            }
        }
    }
    __syncthreads();
    {
        const float m0 = sm_m[0][tid], m1 = sm_m[1][tid];
        const float s0 = sm_s[0][tid], s1 = sm_s[1][tid];
        const float mm = fmaxf(m0, m1);
        const float ss = s0 * __expf(m0 - mm) + s1 * __expf(m1 - mm);
        const int grow = bm + tid;
        pm[(size_t)pan * cMQ + grow] = mm;   // transposed: contiguous per block
        ps[(size_t)pan * cMQ + grow] = ss;
    }

    // bf16 logits into top half of output row slot
    #pragma unroll
    for (int h = 0; h < 2; ++h) {
        #pragma unroll
        for (int mi = 0; mi < 4; ++mi) {
            #pragma unroll
            for (int ni = 0; ni < 4; ++ni) {
                if (!val[ni]) continue;
                const int colg = bn + wn * 64 + ni * 16 + fr;
                #pragma unroll
                for (int r = 0; r < 4; ++r) {
                    const int row = bm + h * 128 + wm * 64 + mi * 16 + g * 4 + r;
                    Cb[(size_t)row * cCBLD + cTOP + colg] = f2bf(acc[h][mi][ni][r]);
                }
            }
        }
    }
}

// ---------------------------------------------------------------------------
// combine partials (transposed pm/ps, 391 panels) -> rowadd.
// Block = 64 rows x 4 panel-stripes; coalesced. (r13-proven.)
// ---------------------------------------------------------------------------
__global__ __launch_bounds__(256) void combine_kernel(
    const float* __restrict__ pm, const float* __restrict__ ps,
    const float* __restrict__ pgen, float* __restrict__ rowadd)
{
    const int lane = threadIdx.x & 63;
    const int wv   = threadIdx.x >> 6;    // panel stripe 0..3
    const int row  = blockIdx.x * 64 + lane;

    float m = -1e30f, s = 0.f;
    #pragma unroll 2
    for (int i = wv; i < cPAN; i += 4) {
        const float mi = pm[(size_t)i * cMQ + row];
        const float si = ps[(size_t)i * cMQ + row];
        const float nm = fmaxf(m, mi);
        s = s * __expf(m - nm) + si * __expf(mi - nm);
        m = nm;
    }
    __shared__ float rm[4][64], rs[4][64];
    rm[wv][lane] = m; rs[wv][lane] = s;
    __syncthreads();
    if (wv == 0) {
        m = rm[0][lane]; s = rs[0][lane];
        #pragma unroll
        for (int i = 1; i < 4; ++i) {
            const float m2 = rm[i][lane], s2 = rs[i][lane];
            const float nm = fmaxf(m, m2);
            s = s * __expf(m - nm) + s2 * __expf(m2 - nm);
            m = nm;
        }
        rowadd[row] = __logf(pgen[row]) - m - __logf(s);
    }
}

// ---------------------------------------------------------------------------
// 4-batch register-phase in-place transform + fused scatter fixup. (r13.)
// ---------------------------------------------------------------------------
__global__ __launch_bounds__(512) void transform_reg(
    float* __restrict__ out, const float* __restrict__ rowadd,
    const int* __restrict__ ebev, const float* __restrict__ attn)
{
    const int row = blockIdx.x;
    const int b   = row / cT;
    const int tid = threadIdx.x;
    constexpr float LOGMIN = -20.72326583694641f;   // log(1e-9)
    constexpr int NCHUNK = cV / 8;                  // 6250

    __shared__ int   pos[cS];
    __shared__ float add[cS];
    for (int s = tid; s < cS; s += 512) {
        pos[s] = ebev[b * cS + s];
        add[s] = attn[(size_t)row * cS + s];
    }

    const float a = rowadd[row];
    const ushort* rowu = (const ushort*)out + (size_t)row * cCBLD + cTOP;
    float* rowf = out + (size_t)row * cVEXT;

    constexpr int BLO[5] = {0, 4, 7, 10, 13};
    #pragma unroll
    for (int bb = 0; bb < 4; ++bb) {
        ushort4 lo[4], hi[4];
        #pragma unroll
        for (int s = 0; s < 4; ++s) {
            const int t = BLO[bb] + s;
            if (t < BLO[bb + 1]) {
                const int cidx = t * 512 + tid;
                if (cidx < NCHUNK) {
                    lo[s] = *(const ushort4*)(rowu + (size_t)cidx * 8);
                    hi[s] = *(const ushort4*)(rowu + (size_t)cidx * 8 + 4);
                }
            }
        }
        __syncthreads();   // all batch reads landed before any batch write
        #pragma unroll
        for (int s = 0; s < 4; ++s) {
            const int t = BLO[bb] + s;
            if (t < BLO[bb + 1]) {
                const int cidx = t * 512 + tid;
                if (cidx < NCHUNK) {
                    const int jb = cidx * 8;
                    float2 o;
                    o.x = fmaxf(bf2f(lo[s].x) + a, LOGMIN);
                    o.y = fmaxf(bf2f(lo[s].y) + a, LOGMIN);
                    *(float2*)(rowf + jb) = o;
                    o.x = fmaxf(bf2f(lo[s].z) + a, LOGMIN);
                    o.y = fmaxf(bf2f(lo[s].w) + a, LOGMIN);
                    *(float2*)(rowf + jb + 2) = o;
                    o.x = fmaxf(bf2f(hi[s].x) + a, LOGMIN);
                    o.y = fmaxf(bf2f(hi[s].y) + a, LOGMIN);
                    *(float2*)(rowf + jb + 4) = o;
                    o.x = fmaxf(bf2f(hi[s].z) + a, LOGMIN);
                    o.y = fmaxf(bf2f(hi[s].w) + a, LOGMIN);
                    *(float2*)(rowf + jb + 6) = o;
                }
            }
        }
    }
    if (tid < (cVEXT - cV) / 2) {   // LOGMIN tail [50000, 50050)
        float2 z; z.x = LOGMIN; z.y = LOGMIN;
        *(float2*)(rowf + cV + 2 * tid) = z;
    }
    __syncthreads();

    // scatter fixup
    for (int s = tid; s < cS; s += 512) {
        const int p = pos[s];
        bool leader = true;
        for (int s2 = 0; s2 < s; ++s2)
            if (pos[s2] == p) { leader = false; break; }
        if (!leader) continue;
        float sum = add[s];
        for (int s2 = s + 1; s2 < cS; ++s2)
            if (pos[s2] == p) sum += add[s2];
        const float base = __expf(rowf[p]);   // clamped; error << threshold
        rowf[p] = __logf(fmaxf(base + sum, 1e-9f));
    }
}

// ---------------------------------------------------------------------------
// attention distribution (scaled by 1-pgen) with FUSED p_gen computation.
// Computes pgen[row] = sigmoid(x[row].pgen_w + pgen_b) as a side output.
// ---------------------------------------------------------------------------
__global__ __launch_bounds__(256) void attn_kernel(
    const float* __restrict__ q, const float* __restrict__ k,
    const int* __restrict__ src_mask,
    const float* __restrict__ x, const float* __restrict__ pgw,
    const float* __restrict__ pgb,
    float* __restrict__ pgen, float* __restrict__ attn)
{
    constexpr float scale = 0.04419417382415922f;  // 1/sqrt(512)
    const int row = blockIdx.x;      // b*T + t
    const int b = row / cT;
    const int tid = threadIdx.x;

    __shared__ __align__(16) float qs[cD];
    __shared__ float sc[cS];
    __shared__ float red[4];
    __shared__ float spg;

    // stage q row + pgen partial dot
    float pg = 0.f;
    for (int i = tid; i < cD; i += 256) {
        qs[i] = q[(size_t)row * cD + i];
        pg += x[(size_t)row * cD + i] * pgw[i];
    }
    #pragma unroll
    for (int off = 32; off; off >>= 1) pg += __shfl_down(pg, off);
    if ((tid & 63) == 0) red[tid >> 6] = pg;
    __syncthreads();
    if (tid == 0) {
        const float d = red[0] + red[1] + red[2] + red[3];
        const float pv = 1.f / (1.f + __expf(-(d + pgb[0])));
        pgen[row] = pv;
        spg = pv;
    }
    __syncthreads();

    for (int s = tid; s < cS; s += 256) {
        const float* kr = k + ((size_t)b * cS + s) * cD;
        float dot = 0.f;
        #pragma unroll 4
        for (int i = 0; i < cD; i += 4) {
            float4 kv = *(const float4*)(kr + i);
            float4 qv = *(const float4*)(qs + i);
            dot += qv.x * kv.x + qv.y * kv.y + qv.z * kv.z + qv.w * kv.w;
        }
        float v = dot * scale;
        if (src_mask[b * cS + s] == 0) v = -1e9f;
        sc[s] = v;
    }
    __syncthreads();

    float m = -3.4e38f;
    for (int s = tid; s < cS; s += 256) m = fmaxf(m, sc[s]);
    #pragma unroll
    for (int off = 32; off; off >>= 1) m = fmaxf(m, __shfl_down(m, off));
    if ((tid & 63) == 0) red[tid >> 6] = m;
    __syncthreads();
    m = fmaxf(fmaxf(red[0], red[1]), fmaxf(red[2], red[3]));
    __syncthreads();

    float sum = 0.f;
    for (int s = tid; s < cS; s += 256) {
        float e = __expf(sc[s] - m);
        sc[s] = e;
        sum += e;
    }
    #pragma unroll
    for (int off = 32; off; off >>= 1) sum += __shfl_down(sum, off);
    if ((tid & 63) == 0) red[tid >> 6] = sum;
    __syncthreads();
    sum = red[0] + red[1] + red[2] + red[3];

    const float w = (1.f - spg) / sum;
    for (int s = tid; s < cS; s += 256)
        attn[(size_t)row * cS + s] = sc[s] * w;
}

extern "C" void kernel_launch(void* const* d_in, const int* in_sizes, int n_in,
                              void* d_out, int out_size, void* d_ws, size_t ws_size,
                              hipStream_t stream)
{
    const float* x      = (const float*)d_in[0];   // (B,T,D)
    const float* enc    = (const float*)d_in[1];   // (B,S,D)
    const int*   mask   = (const int*)d_in[2];     // (B,1,S)
    const int*   ebev   = (const int*)d_in[3];     // (B,S)
    const float* fc_w   = (const float*)d_in[5];   // (V,D)
    const float* fc_b   = (const float*)d_in[6];   // (V,)
    const float* pgen_w = (const float*)d_in[7];   // (1,D)
    const float* pgen_b = (const float*)d_in[8];   // (1,)
    const float* wq     = (const float*)d_in[9];   // (D,D)
    const float* bq     = (const float*)d_in[10];  // (D,)
    const float* wk     = (const float*)d_in[11];  // (D,D)
    const float* bk     = (const float*)d_in[12];  // (D,)
    float* out = (float*)d_out;

    // workspace layout (~68 MB; fits as in prior rounds)
    float* ws     = (float*)d_ws;
    float* q      = ws;                                   // 1024*512
    float* kbuf   = q + (size_t)cB * cT * cD;             // 1600*512
    float* pgen   = kbuf + (size_t)cB * cS * cD;          // 1024
    float* attn   = pgen + cB * cT;                       // 1024*400
    float* pm     = attn + (size_t)cB * cT * cS;          // 391*1024 (transposed)
    float* ps     = pm + (size_t)cPAN * cMQ;              // 391*1024
    float* rowadd = ps + (size_t)cPAN * cMQ;              // 1024
    ushort* xb    = (ushort*)(rowadd + cMQ);
    ushort* encb  = xb + (size_t)cB * cT * cD;
    ushort* wqb   = encb + (size_t)cB * cS * cD;
    ushort* wkb   = wqb + (size_t)cD * cD;
    ushort* wb    = wkb + (size_t)cD * cD;                // V*D bf16 (51 MB)

    const dim3 blk(256);
    const int MQ = cMQ;        // 1024
    const int MK = cB * cS;    // 1600

    // casts: one fused launch (x, enc, wq, wk) + one big (fc_w)
    cast4_kernel<<<dim3(768), blk, 0, stream>>>(
        x, xb, (cB * cT * cD) / 4,
        enc, encb, (cB * cS * cD) / 4,
        wq, wqb, (cD * cD) / 4,
        wk, wkb, (cD * cD) / 4);
    cast_kernel<<<dim3(2048), blk, 0, stream>>>(fc_w, wb, (cV * cD) / 4);

    // projections (bf16 MFMA, fp32 out)
    gemm_proj<<<dim3(MQ / 128, cD / 128), blk, 0, stream>>>(
        xb, wqb, bq, q, MQ, cD, cD, cD);
    gemm_proj<<<dim3((MK + 127) / 128, cD / 128), blk, 0, stream>>>(
        encb, wkb, bk, kbuf, MK, cD, cD, cD);

    // attention distribution (pgen fused in)
    attn_kernel<<<dim3(MQ), blk, 0, stream>>>(
        q, kbuf, mask, x, pgen_w, pgen_b, pgen, attn);

    // big logits GEMM (tall 256x128 tile): bf16 logits into row-slot top half
    gemm_big<<<dim3(4, cPAN), blk, 0, stream>>>(
        xb, wb, fc_b, (ushort*)out, pm, ps);

    // combine partials -> rowadd
    combine_kernel<<<dim3(MQ / 64), blk, 0, stream>>>(pm, ps, pgen, rowadd);

    // 4-batch register-phase in-place expand + fused scatter fixup
    transform_reg<<<dim3(MQ), dim3(512), 0, stream>>>(out, rowadd, ebev, attn);
}